// Round 12
// baseline (240.712 us; speedup 1.0000x reference)
//
#include <hip/hip_runtime.h>

#define NUM_RELS 19
#define NPB 256        // nodes per bucket (power of 2)
#define NPB_SHIFT 8
#define MAXB 400       // max buckets (N <= 102400)
#define NBLK 512       // partition chunk-blocks (2 blocks/CU)

typedef _Float16 half8 __attribute__((ext_vector_type(8)));
typedef float floatx4 __attribute__((ext_vector_type(4)));

// ---------------- pass A: per-block bucket histogram (also produces bcnt totals) ----------------

__global__ __launch_bounds__(512) void count_kernel(const int* __restrict__ dst,
                                                    int* __restrict__ blkhist,
                                                    int* __restrict__ bcnt,
                                                    int E, int B, int chunk) {
    __shared__ int h[MAXB];
    for (int i = threadIdx.x; i < B; i += 512) h[i] = 0;
    __syncthreads();
    int e0 = blockIdx.x * chunk, e1 = min(E, e0 + chunk);
    for (int e = e0 + (int)threadIdx.x; e < e1; e += 512)
        atomicAdd(&h[dst[e] >> NPB_SHIFT], 1);
    __syncthreads();
    for (int i = threadIdx.x; i < B; i += 512) {
        blkhist[blockIdx.x * B + i] = h[i];  // [block][bucket]: contiguous writes
        if (h[i]) atomicAdd(&bcnt[i], h[i]);
    }
}

// ---------------- bucket scan: pbase = exclusive scan of 8-aligned counts ----------------

__global__ __launch_bounds__(512) void bscan_kernel(const int* __restrict__ bcnt,
                                                    int* __restrict__ pbase, int B) {
    __shared__ int lds[512];
    int t = threadIdx.x;
    int c = (t < B) ? ((bcnt[t] + 7) & ~7) : 0;
    lds[t] = c;
    __syncthreads();
    for (int off = 1; off < 512; off <<= 1) {
        int x = (t >= off) ? lds[t - off] : 0;
        __syncthreads();
        lds[t] += x;
        __syncthreads();
    }
    if (t < B) pbase[t] = lds[t] - c;
}

// ---------------- pass B prep: per-bucket scan across chunk-blocks -> deterministic offsets ----------------

__global__ __launch_bounds__(NBLK) void offscan_kernel(const int* __restrict__ blkhist,
                                                       const int* __restrict__ pbase,
                                                       int* __restrict__ offs, int B) {
    __shared__ int lds[NBLK];
    int bucket = blockIdx.x;
    int t = threadIdx.x;
    int v = blkhist[t * B + bucket];
    lds[t] = v;
    __syncthreads();
    for (int off = 1; off < NBLK; off <<= 1) {
        int x = (t >= off) ? lds[t - off] : 0;
        __syncthreads();
        lds[t] += x;
        __syncthreads();
    }
    offs[t * B + bucket] = pbase[bucket] + lds[t] - v;
}

// ---------------- pass B: scatter with deterministic offsets (round-11 verified) ----------------

__global__ __launch_bounds__(512) void scatter2_kernel(
    const int* __restrict__ src, const int* __restrict__ dst, const int* __restrict__ etype,
    const int* __restrict__ offs, uint2* __restrict__ recs, int E, int B, int chunk) {
    __shared__ int cur[MAXB];
    for (int i = threadIdx.x; i < B; i += 512) cur[i] = offs[blockIdx.x * B + i];
    __syncthreads();
    int e0 = blockIdx.x * chunk, e1 = min(E, e0 + chunk);
    for (int e = e0 + (int)threadIdx.x; e < e1; e += 512) {
        int d = dst[e];
        int b = d >> NPB_SHIFT;
        int pos = atomicAdd(&cur[b], 1);  // LDS atomic: rank within (block,bucket)
        uint2 rec;
        rec.x = ((unsigned)src[e] << 5) | (unsigned)etype[e];
        rec.y = (unsigned)d;
        recs[pos] = rec;
    }
}

// ---------------- bucket-local counting sort + layer 1 (merged; round-10 verified) ----------------

__global__ __launch_bounds__(256) void bsort_l1_kernel(
    const uint2* __restrict__ recs, const int* __restrict__ pbase, const int* __restrict__ bcnt,
    int* __restrict__ recs2, int* __restrict__ row_start, int* __restrict__ rend,
    const float* __restrict__ W1, const float* __restrict__ b1, float* __restrict__ h1, int N) {
    __shared__ int hist[NPB];
    __shared__ int offsl[NPB];
    __shared__ int cur[NPB];
    __shared__ int cnt2[NPB * NUM_RELS];  // 19.4KB
    __shared__ float W1s[NUM_RELS * 32];
    __shared__ float b1s[32];
    int b = blockIdx.x;
    int p0 = pbase[b], n = bcnt[b];
    int t = threadIdx.x;

    hist[t] = 0;
    for (int i = t; i < NPB * NUM_RELS; i += 256) cnt2[i] = 0;
    for (int i = t; i < NUM_RELS * 32; i += 256) W1s[i] = W1[i];
    if (t < 32) b1s[t] = b1[t];
    __syncthreads();

    for (int i = t; i < n; i += 256) {
        uint2 rec = recs[p0 + i];
        int ln = rec.y & (NPB - 1);
        atomicAdd(&hist[ln], 1);
        atomicAdd(&cnt2[ln * NUM_RELS + (rec.x & 31)], 1);
    }
    __syncthreads();
    int c = hist[t];
    offsl[t] = c;
    __syncthreads();
    for (int off = 1; off < 256; off <<= 1) {
        int x = (t >= off) ? offsl[t - off] : 0;
        __syncthreads();
        offsl[t] += x;
        __syncthreads();
    }
    int start = p0 + offsl[t] - c;  // exclusive
    cur[t] = start;
    int v = (b << NPB_SHIFT) + t;
    if (v < N) {
        row_start[v] = start;
        rend[v] = start + c;
    }
    __syncthreads();
    for (int i = t; i < n; i += 256) {
        uint2 rec = recs[p0 + i];  // L2-hot (just read above)
        int p = atomicAdd(&cur[rec.y & (NPB - 1)], 1);
        recs2[p] = (int)rec.x;
    }

    int o = t & 31, hw = t >> 5;  // 8 half-waves
    int v0 = b << NPB_SHIFT;
    for (int k = hw; k < NPB; k += 8) {
        int vv = v0 + k;
        if (vv >= N) break;
        float acc = b1s[o];
        const int* cp = &cnt2[k * NUM_RELS];
#pragma unroll
        for (int r = 0; r < NUM_RELS; ++r) acc += (float)cp[r] * W1s[r * 32 + o];
        h1[(size_t)vv * 32 + o] = fmaxf(acc, 0.f);
    }
}

// ---------------- W2 -> f16 B-fragment swizzle (round-6 verified) ----------------

__global__ void w2swz_kernel(const float* __restrict__ W2, _Float16* __restrict__ W2F) {
    int idx = blockIdx.x * blockDim.x + threadIdx.x;
    if (idx >= NUM_RELS * 2 * 64 * 8) return;
    int j = idx & 7, lane = (idx >> 3) & 63, nt = (idx >> 9) & 1, r = idx >> 10;
    int k = (lane >> 4) * 8 + j, n = nt * 16 + (lane & 15);
    W2F[idx] = (_Float16)W2[r * 1024 + k * 32 + n];
}

// ---------------- Transform via MFMA: g[r] = h1 @ W2[r]  (f16 output; round-6 verified) ----------------

__global__ __launch_bounds__(256) void transform_kernel(
    const float* __restrict__ h1, const _Float16* __restrict__ W2F,
    _Float16* __restrict__ g, int N) {
    int lane = threadIdx.x & 63;
    int tile = blockIdx.x * 4 + (threadIdx.x >> 6);
    int v0 = tile * 16;
    if (v0 >= N) return;

    const float* hrow = h1 + (size_t)(v0 + (lane & 15)) * 32 + (lane >> 4) * 8;
    float4 p0 = *(const float4*)hrow;
    float4 p1 = *(const float4*)(hrow + 4);
    half8 a;
    a[0] = (_Float16)p0.x; a[1] = (_Float16)p0.y; a[2] = (_Float16)p0.z; a[3] = (_Float16)p0.w;
    a[4] = (_Float16)p1.x; a[5] = (_Float16)p1.y; a[6] = (_Float16)p1.z; a[7] = (_Float16)p1.w;

    floatx4 zero = {0.f, 0.f, 0.f, 0.f};
    int row = (lane >> 4) * 4;
    int col = lane & 15;
    for (int r = 0; r < NUM_RELS; ++r) {
        _Float16* gbase = g + ((size_t)r * N + v0) * 32;
#pragma unroll
        for (int nt = 0; nt < 2; ++nt) {
            half8 bfrag = *(const half8*)(W2F + ((r * 2 + nt) * 64 + lane) * 8);
            floatx4 d = __builtin_amdgcn_mfma_f32_16x16x32_f16(a, bfrag, zero, 0, 0, 0);
#pragma unroll
            for (int reg = 0; reg < 4; ++reg) {
                gbase[(row + reg) * 32 + nt * 16 + col] = (_Float16)d[reg];
            }
        }
    }
}

// ---------------- Edge phase + layer 3 fused: 8-deep load batches ----------------
// Round-11 Little's-law analysis: 4-deep unroll => ~2.2TB/s concurrency ceiling (matched
// measurement exactly). 8 independent shfl->load chains per batch double the in-flight
// 64B requests per wave before the add-tree drains them. ~48 VGPRs — under the 64-cap
// (no spill; WRITE_SIZE is the tripwire).

__global__ __launch_bounds__(1024) void edge23_kernel(
    const _Float16* __restrict__ g, const int* __restrict__ row_start,
    const int* __restrict__ rend, const int* __restrict__ recs2,
    const float* __restrict__ b2, const float* __restrict__ W3, const float* __restrict__ b3,
    float* __restrict__ out, int N) {
    __shared__ float W3s[1024];
    __shared__ float b2s[32], b3s[32];
    W3s[threadIdx.x] = W3[threadIdx.x];
    if (threadIdx.x < 32) {
        b2s[threadIdx.x] = b2[threadIdx.x];
        b3s[threadIdx.x] = b3[threadIdx.x];
    }
    __syncthreads();

    int o = threadIdx.x & 31;
    int hw = blockIdx.x * 32 + (threadIdx.x >> 5);  // node id
    if (hw >= N) return;
    int start = row_start[hw], end = rend[hw];
    const int sN32 = N * 32;  // element stride per relation; max index ~61M fits int

    float acc = b2s[o];
    for (int base = start; base < end; base += 32) {
        int idx = base + o;
        int m_l = (idx < end) ? recs2[idx] : 0;  // coalesced packed (src<<5|etype)
        int cnt = min(32, end - base);
        int j = 0;
        for (; j + 8 <= cnt; j += 8) {
            float x[8];
#pragma unroll
            for (int k = 0; k < 8; ++k) {
                int m = __shfl(m_l, j + k, 32);
                x[k] = (float)g[(m & 31) * sN32 + (m >> 5) * 32 + o];
            }
            acc += (((x[0] + x[1]) + (x[2] + x[3])) + ((x[4] + x[5]) + (x[6] + x[7])));
        }
        for (; j + 4 <= cnt; j += 4) {
            float x[4];
#pragma unroll
            for (int k = 0; k < 4; ++k) {
                int m = __shfl(m_l, j + k, 32);
                x[k] = (float)g[(m & 31) * sN32 + (m >> 5) * 32 + o];
            }
            acc += ((x[0] + x[1]) + (x[2] + x[3]));
        }
        for (; j < cnt; ++j) {
            int m = __shfl(m_l, j, 32);
            acc += (float)g[(m & 31) * sN32 + (m >> 5) * 32 + o];
        }
    }
    float h2v = fmaxf(acc, 0.f);

    float acc3 = b3s[o];
#pragma unroll
    for (int i = 0; i < 32; ++i) {
        float hi = __shfl(h2v, i, 32);
        acc3 = fmaf(hi, W3s[i * 32 + o], acc3);
    }
    out[(size_t)hw * 32 + o] = acc3;
}

// ---------------- Host launcher ----------------

extern "C" void kernel_launch(void* const* d_in, const int* in_sizes, int n_in,
                              void* d_out, int out_size, void* d_ws, size_t ws_size,
                              hipStream_t stream) {
    const int* src   = (const int*)d_in[0];
    const int* dst   = (const int*)d_in[1];
    const int* etype = (const int*)d_in[2];
    const float* W1  = (const float*)d_in[4];
    const float* b1  = (const float*)d_in[5];
    const float* W2  = (const float*)d_in[6];
    const float* b2  = (const float*)d_in[7];
    const float* W3  = (const float*)d_in[8];
    const float* b3  = (const float*)d_in[9];
    float* out = (float*)d_out;

    int E = in_sizes[0];
    int N = out_size / 32;
    int B = (N + NPB - 1) >> NPB_SHIFT;  // 391 for N=100000

    char* ws = (char*)d_ws;
    size_t off = 0;
    auto alloc = [&](size_t bytes) {
        void* p = ws + off;
        off = (off + bytes + 255) & ~(size_t)255;
        return p;
    };
    float* h1      = (float*)alloc((size_t)N * 32 * 4);
    int* bcnt      = (int*)alloc((size_t)MAXB * 4);
    int* pbase     = (int*)alloc((size_t)MAXB * 4);
    int* blkhist   = (int*)alloc((size_t)NBLK * MAXB * 4);
    int* offs      = (int*)alloc((size_t)NBLK * MAXB * 4);
    int* row_start = (int*)alloc((size_t)N * 4);
    int* rend      = (int*)alloc((size_t)N * 4);
    uint2* recs    = (uint2*)alloc(((size_t)E + 8 * MAXB + 64) * 8);
    int* recs2     = (int*)alloc(((size_t)E + 8 * MAXB + 64) * 4);
    _Float16* g    = (_Float16*)alloc((size_t)NUM_RELS * N * 32 * 2);
    _Float16* W2F  = (_Float16*)alloc((size_t)NUM_RELS * 2 * 64 * 8 * 2);

    hipMemsetAsync(bcnt, 0, (size_t)B * 4, stream);

    int chunk = (E + NBLK - 1) / NBLK;
    count_kernel<<<NBLK, 512, 0, stream>>>(dst, blkhist, bcnt, E, B, chunk);
    bscan_kernel<<<1, 512, 0, stream>>>(bcnt, pbase, B);
    offscan_kernel<<<B, NBLK, 0, stream>>>(blkhist, pbase, offs, B);
    scatter2_kernel<<<NBLK, 512, 0, stream>>>(src, dst, etype, offs, recs, E, B, chunk);

    bsort_l1_kernel<<<B, 256, 0, stream>>>(recs, pbase, bcnt, recs2, row_start, rend,
                                           W1, b1, h1, N);

    w2swz_kernel<<<(NUM_RELS * 2 * 64 * 8 + 255) / 256, 256, 0, stream>>>(W2, W2F);
    int ntiles = (N + 15) / 16;
    transform_kernel<<<(ntiles + 3) / 4, 256, 0, stream>>>(h1, W2F, g, N);

    edge23_kernel<<<(N + 31) / 32, 1024, 0, stream>>>(g, row_start, rend, recs2, b2, W3, b3, out, N);
}

// Round 13
// 230.761 us; speedup vs baseline: 1.0431x; 1.0431x over previous
//
#include <hip/hip_runtime.h>

#define NUM_RELS 19
#define NPB 256        // nodes per bucket (power of 2)
#define NPB_SHIFT 8
#define MAXB 400       // max buckets (N <= 102400)
#define NBLK 512       // partition chunk-blocks (2 blocks/CU)

typedef _Float16 half8 __attribute__((ext_vector_type(8)));
typedef float floatx4 __attribute__((ext_vector_type(4)));

// record pack: dstlocal(8b)<<22 | src(17b)<<5 | etype(5b)   (rec < 2^30)
// recs2 = rec & 0x3FFFFF  ->  src<<5 | etype (edge23's proven format, unchanged)

// ---------------- W2 -> f16 B-fragment swizzle + bcnt zero (fused; replaces memset launch) ----------------

__global__ void w2swz_kernel(const float* __restrict__ W2, _Float16* __restrict__ W2F,
                             int* __restrict__ bcnt, int B) {
    int idx = blockIdx.x * blockDim.x + threadIdx.x;
    if (idx < B) bcnt[idx] = 0;
    if (idx >= NUM_RELS * 2 * 64 * 8) return;
    int j = idx & 7, lane = (idx >> 3) & 63, nt = (idx >> 9) & 1, r = idx >> 10;
    int k = (lane >> 4) * 8 + j, n = nt * 16 + (lane & 15);
    W2F[idx] = (_Float16)W2[r * 1024 + k * 32 + n];
}

// ---------------- pass A: per-block bucket histogram (also produces bcnt totals) ----------------

__global__ __launch_bounds__(512) void count_kernel(const int* __restrict__ dst,
                                                    int* __restrict__ blkhist,
                                                    int* __restrict__ bcnt,
                                                    int E, int B, int chunk) {
    __shared__ int h[MAXB];
    for (int i = threadIdx.x; i < B; i += 512) h[i] = 0;
    __syncthreads();
    int e0 = blockIdx.x * chunk, e1 = min(E, e0 + chunk);
    for (int e = e0 + (int)threadIdx.x; e < e1; e += 512)
        atomicAdd(&h[dst[e] >> NPB_SHIFT], 1);
    __syncthreads();
    for (int i = threadIdx.x; i < B; i += 512) {
        blkhist[blockIdx.x * B + i] = h[i];  // [block][bucket]: contiguous writes
        if (h[i]) atomicAdd(&bcnt[i], h[i]);
    }
}

// ---------------- offsets: pbase (bucket scan, recomputed per block — 400 ints, trivial)
//                  + per-bucket scan across chunk-blocks -> deterministic offsets ----------------

__global__ __launch_bounds__(NBLK) void offscan_kernel(const int* __restrict__ blkhist,
                                                       const int* __restrict__ bcnt,
                                                       int* __restrict__ pbase,
                                                       int* __restrict__ offs, int B) {
    __shared__ int lds[NBLK];
    __shared__ int pbs;
    int bucket = blockIdx.x;
    int t = threadIdx.x;

    // phase 1: pbase[bucket] = exclusive scan of 8-aligned bcnt (replaces bscan kernel)
    int c = (t < B) ? ((bcnt[t] + 7) & ~7) : 0;
    lds[t] = c;
    __syncthreads();
    for (int off = 1; off < NBLK; off <<= 1) {
        int x = (t >= off) ? lds[t - off] : 0;
        __syncthreads();
        lds[t] += x;
        __syncthreads();
    }
    if (t == bucket) {
        pbs = lds[t] - c;
        pbase[bucket] = pbs;
    }
    __syncthreads();
    int myp = pbs;

    // phase 2: scan this bucket's blkhist column across the 512 chunk-blocks
    int v = blkhist[t * B + bucket];
    lds[t] = v;
    __syncthreads();
    for (int off = 1; off < NBLK; off <<= 1) {
        int x = (t >= off) ? lds[t - off] : 0;
        __syncthreads();
        lds[t] += x;
        __syncthreads();
    }
    offs[t * B + bucket] = myp + lds[t] - v;
}

// ---------------- pass B: scatter 4B packed records with deterministic offsets ----------------

__global__ __launch_bounds__(512) void scatter2_kernel(
    const int* __restrict__ src, const int* __restrict__ dst, const int* __restrict__ etype,
    const int* __restrict__ offs, unsigned* __restrict__ recs4, int E, int B, int chunk) {
    __shared__ int cur[MAXB];
    for (int i = threadIdx.x; i < B; i += 512) cur[i] = offs[blockIdx.x * B + i];
    __syncthreads();
    int e0 = blockIdx.x * chunk, e1 = min(E, e0 + chunk);
    for (int e = e0 + (int)threadIdx.x; e < e1; e += 512) {
        int d = dst[e];
        int b = d >> NPB_SHIFT;
        int pos = atomicAdd(&cur[b], 1);  // LDS atomic: rank within (block,bucket)
        recs4[pos] = ((unsigned)(d & (NPB - 1)) << 22) | ((unsigned)src[e] << 5) | (unsigned)etype[e];
    }
}

// ---------------- bucket-local counting sort + layer 1 (merged; h1 now f16) ----------------

__global__ __launch_bounds__(256) void bsort_l1_kernel(
    const unsigned* __restrict__ recs4, const int* __restrict__ pbase, const int* __restrict__ bcnt,
    int* __restrict__ recs2, int* __restrict__ row_start, int* __restrict__ rend,
    const float* __restrict__ W1, const float* __restrict__ b1, _Float16* __restrict__ h1, int N) {
    __shared__ int hist[NPB];
    __shared__ int offsl[NPB];
    __shared__ int cur[NPB];
    __shared__ int cnt2[NPB * NUM_RELS];  // 19.4KB
    __shared__ float W1s[NUM_RELS * 32];
    __shared__ float b1s[32];
    int b = blockIdx.x;
    int p0 = pbase[b], n = bcnt[b];
    int t = threadIdx.x;

    hist[t] = 0;
    for (int i = t; i < NPB * NUM_RELS; i += 256) cnt2[i] = 0;
    for (int i = t; i < NUM_RELS * 32; i += 256) W1s[i] = W1[i];
    if (t < 32) b1s[t] = b1[t];
    __syncthreads();

    for (int i = t; i < n; i += 256) {
        unsigned rec = recs4[p0 + i];
        int ln = rec >> 22;
        atomicAdd(&hist[ln], 1);
        atomicAdd(&cnt2[ln * NUM_RELS + (rec & 31)], 1);
    }
    __syncthreads();
    int c = hist[t];
    offsl[t] = c;
    __syncthreads();
    for (int off = 1; off < 256; off <<= 1) {
        int x = (t >= off) ? offsl[t - off] : 0;
        __syncthreads();
        offsl[t] += x;
        __syncthreads();
    }
    int start = p0 + offsl[t] - c;  // exclusive
    cur[t] = start;
    int v = (b << NPB_SHIFT) + t;
    if (v < N) {
        row_start[v] = start;
        rend[v] = start + c;
    }
    __syncthreads();
    for (int i = t; i < n; i += 256) {
        unsigned rec = recs4[p0 + i];  // L2-hot (just read above)
        int p = atomicAdd(&cur[rec >> 22], 1);
        recs2[p] = (int)(rec & 0x3FFFFFu);  // src<<5 | etype
    }

    int o = t & 31, hw = t >> 5;  // 8 half-waves
    int v0 = b << NPB_SHIFT;
    for (int k = hw; k < NPB; k += 8) {
        int vv = v0 + k;
        if (vv >= N) break;
        float acc = b1s[o];
        const int* cp = &cnt2[k * NUM_RELS];
#pragma unroll
        for (int r = 0; r < NUM_RELS; ++r) acc += (float)cp[r] * W1s[r * 32 + o];
        h1[(size_t)vv * 32 + o] = (_Float16)fmaxf(acc, 0.f);  // f16: same value transform used
    }
}

// ---------------- Transform via MFMA: g[r] = h1 @ W2[r]  (h1 f16: A-frag is ONE 16B load) ----------------

__global__ __launch_bounds__(256) void transform_kernel(
    const _Float16* __restrict__ h1, const _Float16* __restrict__ W2F,
    _Float16* __restrict__ g, int N) {
    int lane = threadIdx.x & 63;
    int tile = blockIdx.x * 4 + (threadIdx.x >> 6);
    int v0 = tile * 16;
    if (v0 >= N) return;

    half8 a = *(const half8*)(h1 + (size_t)(v0 + (lane & 15)) * 32 + (lane >> 4) * 8);

    floatx4 zero = {0.f, 0.f, 0.f, 0.f};
    int row = (lane >> 4) * 4;
    int col = lane & 15;
    for (int r = 0; r < NUM_RELS; ++r) {
        _Float16* gbase = g + ((size_t)r * N + v0) * 32;
#pragma unroll
        for (int nt = 0; nt < 2; ++nt) {
            half8 bfrag = *(const half8*)(W2F + ((r * 2 + nt) * 64 + lane) * 8);
            floatx4 d = __builtin_amdgcn_mfma_f32_16x16x32_f16(a, bfrag, zero, 0, 0, 0);
#pragma unroll
            for (int reg = 0; reg < 4; ++reg) {
                gbase[(row + reg) * 32 + nt * 16 + col] = (_Float16)d[reg];
            }
        }
    }
}

// ---------------- Edge phase + layer 3 fused (structure frozen at its gather roofline;
//                  block 512 for finer tail scheduling) ----------------

__global__ __launch_bounds__(512) void edge23_kernel(
    const _Float16* __restrict__ g, const int* __restrict__ row_start,
    const int* __restrict__ rend, const int* __restrict__ recs2,
    const float* __restrict__ b2, const float* __restrict__ W3, const float* __restrict__ b3,
    float* __restrict__ out, int N) {
    __shared__ float W3s[1024];
    __shared__ float b2s[32], b3s[32];
    for (int i = threadIdx.x; i < 1024; i += 512) W3s[i] = W3[i];
    if (threadIdx.x < 32) {
        b2s[threadIdx.x] = b2[threadIdx.x];
        b3s[threadIdx.x] = b3[threadIdx.x];
    }
    __syncthreads();

    int o = threadIdx.x & 31;
    int hw = blockIdx.x * 16 + (threadIdx.x >> 5);  // node id
    if (hw >= N) return;
    int start = row_start[hw], end = rend[hw];
    const int sN32 = N * 32;  // element stride per relation; max index ~61M fits int

    float acc = b2s[o];
    for (int base = start; base < end; base += 32) {
        int idx = base + o;
        int m_l = (idx < end) ? recs2[idx] : 0;  // coalesced packed (src<<5|etype)
        int cnt = min(32, end - base);
        int j = 0;
        for (; j + 4 <= cnt; j += 4) {
            float x[4];
#pragma unroll
            for (int k = 0; k < 4; ++k) {
                int m = __shfl(m_l, j + k, 32);
                x[k] = (float)g[(m & 31) * sN32 + (m >> 5) * 32 + o];
            }
            acc += ((x[0] + x[1]) + (x[2] + x[3]));
        }
        for (; j < cnt; ++j) {
            int m = __shfl(m_l, j, 32);
            acc += (float)g[(m & 31) * sN32 + (m >> 5) * 32 + o];
        }
    }
    float h2v = fmaxf(acc, 0.f);

    float acc3 = b3s[o];
#pragma unroll
    for (int i = 0; i < 32; ++i) {
        float hi = __shfl(h2v, i, 32);
        acc3 = fmaf(hi, W3s[i * 32 + o], acc3);
    }
    out[(size_t)hw * 32 + o] = acc3;
}

// ---------------- Host launcher ----------------

extern "C" void kernel_launch(void* const* d_in, const int* in_sizes, int n_in,
                              void* d_out, int out_size, void* d_ws, size_t ws_size,
                              hipStream_t stream) {
    const int* src   = (const int*)d_in[0];
    const int* dst   = (const int*)d_in[1];
    const int* etype = (const int*)d_in[2];
    const float* W1  = (const float*)d_in[4];
    const float* b1  = (const float*)d_in[5];
    const float* W2  = (const float*)d_in[6];
    const float* b2  = (const float*)d_in[7];
    const float* W3  = (const float*)d_in[8];
    const float* b3  = (const float*)d_in[9];
    float* out = (float*)d_out;

    int E = in_sizes[0];
    int N = out_size / 32;
    int B = (N + NPB - 1) >> NPB_SHIFT;  // 391 for N=100000

    char* ws = (char*)d_ws;
    size_t off = 0;
    auto alloc = [&](size_t bytes) {
        void* p = ws + off;
        off = (off + bytes + 255) & ~(size_t)255;
        return p;
    };
    _Float16* h1    = (_Float16*)alloc((size_t)N * 32 * 2);
    int* bcnt       = (int*)alloc((size_t)MAXB * 4);
    int* pbase      = (int*)alloc((size_t)MAXB * 4);
    int* blkhist    = (int*)alloc((size_t)NBLK * MAXB * 4);
    int* offs       = (int*)alloc((size_t)NBLK * MAXB * 4);
    int* row_start  = (int*)alloc((size_t)N * 4);
    int* rend       = (int*)alloc((size_t)N * 4);
    unsigned* recs4 = (unsigned*)alloc(((size_t)E + 8 * MAXB + 64) * 4);
    int* recs2      = (int*)alloc(((size_t)E + 8 * MAXB + 64) * 4);
    _Float16* g     = (_Float16*)alloc((size_t)NUM_RELS * N * 32 * 2);
    _Float16* W2F   = (_Float16*)alloc((size_t)NUM_RELS * 2 * 64 * 8 * 2);

    // w2swz also zeroes bcnt (replaces the memset launch); runs before count_kernel
    w2swz_kernel<<<(NUM_RELS * 2 * 64 * 8 + 255) / 256, 256, 0, stream>>>(W2, W2F, bcnt, B);

    int chunk = (E + NBLK - 1) / NBLK;
    count_kernel<<<NBLK, 512, 0, stream>>>(dst, blkhist, bcnt, E, B, chunk);
    offscan_kernel<<<B, NBLK, 0, stream>>>(blkhist, bcnt, pbase, offs, B);
    scatter2_kernel<<<NBLK, 512, 0, stream>>>(src, dst, etype, offs, recs4, E, B, chunk);

    bsort_l1_kernel<<<B, 256, 0, stream>>>(recs4, pbase, bcnt, recs2, row_start, rend,
                                           W1, b1, h1, N);

    int ntiles = (N + 15) / 16;
    transform_kernel<<<(ntiles + 3) / 4, 256, 0, stream>>>(h1, W2F, g, N);

    edge23_kernel<<<(N + 15) / 16, 512, 0, stream>>>(g, row_start, rend, recs2, b2, W3, b3, out, N);
}

// Round 14
// 208.802 us; speedup vs baseline: 1.1528x; 1.1052x over previous
//
#include <hip/hip_runtime.h>

#define NUM_RELS 19
#define NPB 256        // nodes per bucket (power of 2)
#define NPB_SHIFT 8
#define MAXB 400       // max buckets (N <= 102400)
#define NBLK 512       // partition chunk-blocks (2 blocks/CU)

typedef _Float16 half8 __attribute__((ext_vector_type(8)));
typedef float floatx4 __attribute__((ext_vector_type(4)));

// record pack: dstlocal(8b)<<22 | src(17b)<<5 | etype(5b)   (rec < 2^30)
// recs2 = rec & 0x3FFFFF  ->  src<<5 | etype (edge23's proven format)

// ---------------- W2 -> f16 B-fragment swizzle + bcnt zero ----------------

__global__ void w2swz_kernel(const float* __restrict__ W2, _Float16* __restrict__ W2F,
                             int* __restrict__ bcnt, int B) {
    int idx = blockIdx.x * blockDim.x + threadIdx.x;
    if (idx < B) bcnt[idx] = 0;
    if (idx >= NUM_RELS * 2 * 64 * 8) return;
    int j = idx & 7, lane = (idx >> 3) & 63, nt = (idx >> 9) & 1, r = idx >> 10;
    int k = (lane >> 4) * 8 + j, n = nt * 16 + (lane & 15);
    W2F[idx] = (_Float16)W2[r * 1024 + k * 32 + n];
}

// ---------------- pass A: per-block bucket histogram (also produces bcnt totals) ----------------

__global__ __launch_bounds__(512) void count_kernel(const int* __restrict__ dst,
                                                    int* __restrict__ blkhist,
                                                    int* __restrict__ bcnt,
                                                    int E, int B, int chunk) {
    __shared__ int h[MAXB];
    for (int i = threadIdx.x; i < B; i += 512) h[i] = 0;
    __syncthreads();
    int e0 = blockIdx.x * chunk, e1 = min(E, e0 + chunk);
    for (int e = e0 + (int)threadIdx.x; e < e1; e += 512)
        atomicAdd(&h[dst[e] >> NPB_SHIFT], 1);
    __syncthreads();
    for (int i = threadIdx.x; i < B; i += 512) {
        blkhist[blockIdx.x * B + i] = h[i];
        if (h[i]) atomicAdd(&bcnt[i], h[i]);
    }
}

// ---------------- offsets: pbase + per-bucket scan across chunk-blocks ----------------

__global__ __launch_bounds__(NBLK) void offscan_kernel(const int* __restrict__ blkhist,
                                                       const int* __restrict__ bcnt,
                                                       int* __restrict__ pbase,
                                                       int* __restrict__ offs, int B) {
    __shared__ int lds[NBLK];
    __shared__ int pbs;
    int bucket = blockIdx.x;
    int t = threadIdx.x;

    int c = (t < B) ? ((bcnt[t] + 7) & ~7) : 0;
    lds[t] = c;
    __syncthreads();
    for (int off = 1; off < NBLK; off <<= 1) {
        int x = (t >= off) ? lds[t - off] : 0;
        __syncthreads();
        lds[t] += x;
        __syncthreads();
    }
    if (t == bucket) {
        pbs = lds[t] - c;
        pbase[bucket] = pbs;
    }
    __syncthreads();
    int myp = pbs;

    int v = blkhist[t * B + bucket];
    lds[t] = v;
    __syncthreads();
    for (int off = 1; off < NBLK; off <<= 1) {
        int x = (t >= off) ? lds[t - off] : 0;
        __syncthreads();
        lds[t] += x;
        __syncthreads();
    }
    offs[t * B + bucket] = myp + lds[t] - v;
}

// ---------------- pass B: scatter 4B packed records with deterministic offsets ----------------

__global__ __launch_bounds__(512) void scatter2_kernel(
    const int* __restrict__ src, const int* __restrict__ dst, const int* __restrict__ etype,
    const int* __restrict__ offs, unsigned* __restrict__ recs4, int E, int B, int chunk) {
    __shared__ int cur[MAXB];
    for (int i = threadIdx.x; i < B; i += 512) cur[i] = offs[blockIdx.x * B + i];
    __syncthreads();
    int e0 = blockIdx.x * chunk, e1 = min(E, e0 + chunk);
    for (int e = e0 + (int)threadIdx.x; e < e1; e += 512) {
        int d = dst[e];
        int b = d >> NPB_SHIFT;
        int pos = atomicAdd(&cur[b], 1);
        recs4[pos] = ((unsigned)(d & (NPB - 1)) << 22) | ((unsigned)src[e] << 5) | (unsigned)etype[e];
    }
}

// ---------------- bucket sort + layer1 + MFMA transform, fully fused ----------------
// Per bucket (512 threads): hist+cnt2 pass, scan, scatter recs2, h1 tile computed into
// LDS (never touches HBM), then the bucket's 16 node-tiles of g[r] = h1 @ W2[r] via MFMA
// (round-6-proven fragment layouts). Replaces round-13's bsort_l1 + transform pair:
// -1 dispatch, -12.8MB h1 HBM round-trip.

__global__ __launch_bounds__(512) void bsort_l1t_kernel(
    const unsigned* __restrict__ recs4, const int* __restrict__ pbase, const int* __restrict__ bcnt,
    int* __restrict__ recs2, int* __restrict__ row_start, int* __restrict__ rend,
    const float* __restrict__ W1, const float* __restrict__ b1,
    const _Float16* __restrict__ W2F, _Float16* __restrict__ g, int N) {
    __shared__ int hist[NPB];
    __shared__ int offsl[NPB];
    __shared__ int cur[NPB];
    __shared__ int cnt2[NPB * NUM_RELS];     // 19.4KB
    __shared__ float W1s[NUM_RELS * 32];
    __shared__ float b1s[32];
    __shared__ _Float16 h1t[NPB * 32];       // 16KB bucket h1 tile
    int b = blockIdx.x;
    int p0 = pbase[b], n = bcnt[b];
    int t = threadIdx.x;

    if (t < NPB) hist[t] = 0;
    for (int i = t; i < NPB * NUM_RELS; i += 512) cnt2[i] = 0;
    for (int i = t; i < NUM_RELS * 32; i += 512) W1s[i] = W1[i];
    if (t < 32) b1s[t] = b1[t];
    __syncthreads();

    for (int i = t; i < n; i += 512) {
        unsigned rec = recs4[p0 + i];
        int ln = rec >> 22;
        atomicAdd(&hist[ln], 1);
        atomicAdd(&cnt2[ln * NUM_RELS + (rec & 31)], 1);
    }
    __syncthreads();
    int c = 0;
    if (t < NPB) {
        c = hist[t];
        offsl[t] = c;
    }
    __syncthreads();
    for (int off = 1; off < NPB; off <<= 1) {
        int x = 0;
        if (t < NPB && t >= off) x = offsl[t - off];
        __syncthreads();
        if (t < NPB) offsl[t] += x;
        __syncthreads();
    }
    if (t < NPB) {
        int start = p0 + offsl[t] - c;  // exclusive
        cur[t] = start;
        int v = (b << NPB_SHIFT) + t;
        if (v < N) {
            row_start[v] = start;
            rend[v] = start + c;
        }
    }
    __syncthreads();
    for (int i = t; i < n; i += 512) {
        unsigned rec = recs4[p0 + i];  // L2-hot (just read above)
        int p = atomicAdd(&cur[rec >> 22], 1);
        recs2[p] = (int)(rec & 0x3FFFFFu);  // src<<5 | etype
    }

    // layer 1 into the LDS tile (f16, identical rounding to round-13's global h1)
    int o = t & 31, hw = t >> 5;  // 16 half-waves
    int v0n = b << NPB_SHIFT;
    for (int k = hw; k < NPB; k += 16) {
        int vv = v0n + k;
        float acc = b1s[o];
        const int* cp = &cnt2[k * NUM_RELS];
#pragma unroll
        for (int r = 0; r < NUM_RELS; ++r) acc += (float)cp[r] * W1s[r * 32 + o];
        h1t[k * 32 + o] = (vv < N) ? (_Float16)fmaxf(acc, 0.f) : (_Float16)0.f;
    }
    __syncthreads();

    // MFMA transform for this bucket's 16 node-tiles (N % 16 == 0: per-tile guard only)
    int lane = t & 63;
    int wv = t >> 6;  // 8 waves
    floatx4 zero = {0.f, 0.f, 0.f, 0.f};
    int row = (lane >> 4) * 4;
    int col = lane & 15;
    for (int tile = wv; tile < NPB / 16; tile += 8) {
        int v0g = v0n + tile * 16;
        if (v0g >= N) continue;
        half8 a = *(const half8*)(h1t + (tile * 16 + (lane & 15)) * 32 + (lane >> 4) * 8);
        for (int r = 0; r < NUM_RELS; ++r) {
            _Float16* gbase = g + ((size_t)r * N + v0g) * 32;
#pragma unroll
            for (int nt = 0; nt < 2; ++nt) {
                half8 bfrag = *(const half8*)(W2F + ((r * 2 + nt) * 64 + lane) * 8);
                floatx4 d = __builtin_amdgcn_mfma_f32_16x16x32_f16(a, bfrag, zero, 0, 0, 0);
#pragma unroll
                for (int reg = 0; reg < 4; ++reg) {
                    gbase[(row + reg) * 32 + nt * 16 + col] = (_Float16)d[reg];
                }
            }
        }
    }
}

// ---------------- Edge phase + layer 3 fused (frozen at its gather roofline) ----------------

__global__ __launch_bounds__(512) void edge23_kernel(
    const _Float16* __restrict__ g, const int* __restrict__ row_start,
    const int* __restrict__ rend, const int* __restrict__ recs2,
    const float* __restrict__ b2, const float* __restrict__ W3, const float* __restrict__ b3,
    float* __restrict__ out, int N) {
    __shared__ float W3s[1024];
    __shared__ float b2s[32], b3s[32];
    for (int i = threadIdx.x; i < 1024; i += 512) W3s[i] = W3[i];
    if (threadIdx.x < 32) {
        b2s[threadIdx.x] = b2[threadIdx.x];
        b3s[threadIdx.x] = b3[threadIdx.x];
    }
    __syncthreads();

    int o = threadIdx.x & 31;
    int hw = blockIdx.x * 16 + (threadIdx.x >> 5);  // node id
    if (hw >= N) return;
    int start = row_start[hw], end = rend[hw];
    const int sN32 = N * 32;

    float acc = b2s[o];
    for (int base = start; base < end; base += 32) {
        int idx = base + o;
        int m_l = (idx < end) ? recs2[idx] : 0;
        int cnt = min(32, end - base);
        int j = 0;
        for (; j + 4 <= cnt; j += 4) {
            float x[4];
#pragma unroll
            for (int k = 0; k < 4; ++k) {
                int m = __shfl(m_l, j + k, 32);
                x[k] = (float)g[(m & 31) * sN32 + (m >> 5) * 32 + o];
            }
            acc += ((x[0] + x[1]) + (x[2] + x[3]));
        }
        for (; j < cnt; ++j) {
            int m = __shfl(m_l, j, 32);
            acc += (float)g[(m & 31) * sN32 + (m >> 5) * 32 + o];
        }
    }
    float h2v = fmaxf(acc, 0.f);

    float acc3 = b3s[o];
#pragma unroll
    for (int i = 0; i < 32; ++i) {
        float hi = __shfl(h2v, i, 32);
        acc3 = fmaf(hi, W3s[i * 32 + o], acc3);
    }
    out[(size_t)hw * 32 + o] = acc3;
}

// ---------------- Host launcher ----------------

extern "C" void kernel_launch(void* const* d_in, const int* in_sizes, int n_in,
                              void* d_out, int out_size, void* d_ws, size_t ws_size,
                              hipStream_t stream) {
    const int* src   = (const int*)d_in[0];
    const int* dst   = (const int*)d_in[1];
    const int* etype = (const int*)d_in[2];
    const float* W1  = (const float*)d_in[4];
    const float* b1  = (const float*)d_in[5];
    const float* W2  = (const float*)d_in[6];
    const float* b2  = (const float*)d_in[7];
    const float* W3  = (const float*)d_in[8];
    const float* b3  = (const float*)d_in[9];
    float* out = (float*)d_out;

    int E = in_sizes[0];
    int N = out_size / 32;
    int B = (N + NPB - 1) >> NPB_SHIFT;  // 391 for N=100000

    char* ws = (char*)d_ws;
    size_t off = 0;
    auto alloc = [&](size_t bytes) {
        void* p = ws + off;
        off = (off + bytes + 255) & ~(size_t)255;
        return p;
    };
    int* bcnt       = (int*)alloc((size_t)MAXB * 4);
    int* pbase      = (int*)alloc((size_t)MAXB * 4);
    int* blkhist    = (int*)alloc((size_t)NBLK * MAXB * 4);
    int* offs       = (int*)alloc((size_t)NBLK * MAXB * 4);
    int* row_start  = (int*)alloc((size_t)N * 4);
    int* rend       = (int*)alloc((size_t)N * 4);
    unsigned* recs4 = (unsigned*)alloc(((size_t)E + 8 * MAXB + 64) * 4);
    int* recs2      = (int*)alloc(((size_t)E + 8 * MAXB + 64) * 4);
    _Float16* g     = (_Float16*)alloc((size_t)NUM_RELS * N * 32 * 2);
    _Float16* W2F   = (_Float16*)alloc((size_t)NUM_RELS * 2 * 64 * 8 * 2);

    w2swz_kernel<<<(NUM_RELS * 2 * 64 * 8 + 255) / 256, 256, 0, stream>>>(W2, W2F, bcnt, B);

    int chunk = (E + NBLK - 1) / NBLK;
    count_kernel<<<NBLK, 512, 0, stream>>>(dst, blkhist, bcnt, E, B, chunk);
    offscan_kernel<<<B, NBLK, 0, stream>>>(blkhist, bcnt, pbase, offs, B);
    scatter2_kernel<<<NBLK, 512, 0, stream>>>(src, dst, etype, offs, recs4, E, B, chunk);

    bsort_l1t_kernel<<<B, 512, 0, stream>>>(recs4, pbase, bcnt, recs2, row_start, rend,
                                            W1, b1, W2F, g, N);

    edge23_kernel<<<(N + 15) / 16, 512, 0, stream>>>(g, row_start, rend, recs2, b2, W3, b3, out, N);
}